// Round 2
// baseline (212.236 us; speedup 1.0000x reference)
//
#include <hip/hip_runtime.h>
#include <stdint.h>

#define GMAX 128
#define TK 128            // top-k per mask (FG_ROIS_PER_IMAGE = BG_ROIS_PER_IMAGE = 128)
#define NBINS 4096
#define CAND_MAX 4096
#define SEL_THREADS 1024
#define NUM_CLASSES 21

// ---------------------------------------------------------------------------
// JAX threefry2x32 block cipher (key = [hi32(seed), lo32(seed)] = [0, 42])
// ---------------------------------------------------------------------------
__device__ __forceinline__ void threefry2x32(uint32_t k0, uint32_t k1,
                                             uint32_t& x0, uint32_t& x1) {
  uint32_t ks0 = k0, ks1 = k1, ks2 = k0 ^ k1 ^ 0x1BD11BDAu;
  x0 += ks0; x1 += ks1;
#define TF_ROUND(r) { x0 += x1; x1 = (x1 << (r)) | (x1 >> (32 - (r))); x1 ^= x0; }
  TF_ROUND(13) TF_ROUND(15) TF_ROUND(26) TF_ROUND(6)
  x0 += ks1; x1 += ks2 + 1u;
  TF_ROUND(17) TF_ROUND(29) TF_ROUND(16) TF_ROUND(24)
  x0 += ks2; x1 += ks0 + 2u;
  TF_ROUND(13) TF_ROUND(15) TF_ROUND(26) TF_ROUND(6)
  x0 += ks0; x1 += ks1 + 3u;
  TF_ROUND(17) TF_ROUND(29) TF_ROUND(16) TF_ROUND(24)
  x0 += ks1; x1 += ks2 + 4u;
  TF_ROUND(13) TF_ROUND(15) TF_ROUND(26) TF_ROUND(6)
  x0 += ks2; x1 += ks0 + 5u;
#undef TF_ROUND
}

// ---------------------------------------------------------------------------
// Kernel 1: per-ROI max-IoU, argmax (first-max), threefry uniform -> packed
// score word:  [ubits23 << 9 | gt_assignment(7b) << 2 | fg << 1 | bg]
//
// PRNG: JAX *partitionable* threefry (default since jax 0.4.36):
//   bits[i] = b0 ^ b1 where (b0,b1) = threefry2x32(key=(0,42), x=(0, i))
//   (iota_2x32_shape gives hi=0, lo=i for M < 2^32; 32-bit path XORs outputs)
// ---------------------------------------------------------------------------
__global__ void __launch_bounds__(256)
score_kernel(const float* __restrict__ all_rois,   // [N,5]
             const float* __restrict__ gt_boxes,   // [G,4]
             uint32_t* __restrict__ score,         // [M]
             int N, int M, int G) {
  __shared__ float sgx1[GMAX], sgy1[GMAX], sgx2[GMAX], sgy2[GMAX], sga[GMAX];
  const int t = threadIdx.x;
  if (t < G) {
    float x1 = gt_boxes[t * 4 + 0];
    float y1 = gt_boxes[t * 4 + 1];
    float x2 = gt_boxes[t * 4 + 2];
    float y2 = gt_boxes[t * 4 + 3];
    sgx1[t] = x1; sgy1[t] = y1; sgx2[t] = x2; sgy2[t] = y2;
    sga[t] = __fmul_rn(__fadd_rn(__fsub_rn(x2, x1), 1.0f),
                       __fadd_rn(__fsub_rn(y2, y1), 1.0f));
  }
  __syncthreads();
  const int i = blockIdx.x * 256 + t;
  if (i >= M) return;

  float bx1, by1, bx2, by2;
  if (i < N) {
    bx1 = all_rois[(size_t)i * 5 + 1];
    by1 = all_rois[(size_t)i * 5 + 2];
    bx2 = all_rois[(size_t)i * 5 + 3];
    by2 = all_rois[(size_t)i * 5 + 4];
  } else {
    int g = i - N;
    bx1 = sgx1[g]; by1 = sgy1[g]; bx2 = sgx2[g]; by2 = sgy2[g];
  }
  const float area = __fmul_rn(__fadd_rn(__fsub_rn(bx2, bx1), 1.0f),
                               __fadd_rn(__fsub_rn(by2, by1), 1.0f));
  float best = -1.0f;
  int bi = 0;
  for (int g = 0; g < G; ++g) {
    float ix1 = fmaxf(bx1, sgx1[g]);
    float iy1 = fmaxf(by1, sgy1[g]);
    float ix2 = fminf(bx2, sgx2[g]);
    float iy2 = fminf(by2, sgy2[g]);
    float iw = fmaxf(__fadd_rn(__fsub_rn(ix2, ix1), 1.0f), 0.0f);
    float ih = fmaxf(__fadd_rn(__fsub_rn(iy2, iy1), 1.0f), 0.0f);
    float inter = __fmul_rn(iw, ih);
    float uni = __fsub_rn(__fadd_rn(area, sga[g]), inter);
    float ov = __fdiv_rn(inter, uni);               // IEEE-rounded, matches XLA fdiv
    if (ov > best) { best = ov; bi = g; }           // first-max == jnp.argmax
  }

  // partitionable threefry: counter (hi=0, lo=i), output = x0 ^ x1
  uint32_t cx0 = 0u, cx1 = (uint32_t)i;
  threefry2x32(0u, 42u, cx0, cx1);
  uint32_t bits = cx0 ^ cx1;
  uint32_t ubits = bits >> 9;                        // mantissa of u in [0,1)

  uint32_t fg = (best >= 0.5f) ? 1u : 0u;
  uint32_t bg = (!fg && best >= 0.1f) ? 1u : 0u;
  score[i] = (ubits << 9) | ((uint32_t)bi << 2) | (fg << 1) | bg;
}

// ---------------------------------------------------------------------------
// Kernel 2: stable top-128 per mask (block 0 = fg, block 1 = bg).
// Histogram over top-12 mantissa bits -> threshold bin -> compact -> bitonic.
// Composite key ((ubits+1)<<32)|~i reproduces XLA top_k tie-breaking and the
// where(mask, u, -1.0) padding semantics exactly.
// ---------------------------------------------------------------------------
__global__ void __launch_bounds__(SEL_THREADS)
select_kernel(const uint32_t* __restrict__ score, int M,
              int* __restrict__ keep,          // [2*TK]
              int* __restrict__ fgvalid) {     // [TK]
  const uint32_t mask_bit = (blockIdx.x == 0) ? 2u : 1u;
  __shared__ uint32_t hist[NBINS];
  __shared__ uint32_t gs[SEL_THREADS];
  __shared__ uint64_t cand[CAND_MAX];
  __shared__ int s_jstar, s_B, s_cnt;
  const int t = threadIdx.x;

  for (int b = t; b < NBINS; b += SEL_THREADS) hist[b] = 0u;
  if (t == 0) { s_jstar = -1; s_cnt = 0; }
  __syncthreads();

  // histogram of masked elements over bin = ubits >> 11 = score >> 20
#pragma unroll 4
  for (int i = t; i < M; i += SEL_THREADS) {
    uint32_t s = score[i];
    if (s & mask_bit) atomicAdd(&hist[s >> 20], 1u);
  }
  __syncthreads();

  // group sums (4 bins / thread) + parallel inclusive suffix scan
  gs[t] = hist[4 * t] + hist[4 * t + 1] + hist[4 * t + 2] + hist[4 * t + 3];
  __syncthreads();
  for (int d = 1; d < SEL_THREADS; d <<= 1) {
    uint32_t add = (t + d < SEL_THREADS) ? gs[t + d] : 0u;
    __syncthreads();
    gs[t] += add;
    __syncthreads();
  }
  // gs[t] = count of masked elements with bin >= 4t (non-increasing in t)
  if (gs[t] >= (uint32_t)TK &&
      (t == SEL_THREADS - 1 || gs[t + 1] < (uint32_t)TK))
    s_jstar = t;
  __syncthreads();
  if (t == 0) {
    if (s_jstar < 0) {
      s_B = -1;                       // fewer than TK valid -> fallback
    } else {
      int j = s_jstar;
      uint32_t base = (j < SEL_THREADS - 1) ? gs[j + 1] : 0u;
      int B = 4 * j;
      for (int b = 4 * j + 3; b >= 4 * j; --b) {
        base += hist[b];
        if (base >= (uint32_t)TK) { B = b; break; }
      }
      s_B = B;
    }
  }
  __syncthreads();
  const int Bth = s_B;

  // compact candidates (bin >= Bth, or all valid in fallback)
#pragma unroll 4
  for (int i = t; i < M; i += SEL_THREADS) {
    uint32_t s = score[i];
    if ((s & mask_bit) && (Bth < 0 || (int)(s >> 20) >= Bth)) {
      int p = atomicAdd(&s_cnt, 1);
      if (p < CAND_MAX)
        cand[p] = (((uint64_t)((s >> 9) + 1u)) << 32) | (uint64_t)(~(uint32_t)i);
    }
  }
  __syncthreads();
  int cnt = s_cnt; if (cnt > CAND_MAX) cnt = CAND_MAX;
  int P = TK;
  while (P < cnt) P <<= 1;
  for (int p = cnt + t; p < P; p += SEL_THREADS) cand[p] = 0ull;
  __syncthreads();

  // bitonic sort, descending
  for (int k = 2; k <= P; k <<= 1) {
    for (int j = k >> 1; j > 0; j >>= 1) {
      for (int idx = t; idx < P; idx += SEL_THREADS) {
        int l = idx ^ j;
        if (l > idx) {
          uint64_t a = cand[idx], b = cand[l];
          bool swp = ((idx & k) == 0) ? (a < b) : (a > b);
          if (swp) { cand[idx] = b; cand[l] = a; }
        }
      }
      __syncthreads();
    }
  }

  // fallback: pad with lowest-index non-masked elements (JAX -1.0 ties)
  if (Bth < 0) {
    if (t == 0) {
      int fill = cnt;
      for (int i = 0; i < M && fill < TK; ++i)
        if (!(score[i] & mask_bit))
          cand[fill++] = (uint64_t)(~(uint32_t)i);   // high word 0 => invalid
    }
    __syncthreads();
  }

  const int out = (blockIdx.x == 0) ? 0 : TK;
  if (t < TK) {
    uint64_t c = cand[t];
    int idx = (int)(~(uint32_t)(c & 0xFFFFFFFFull));
    keep[out + t] = idx;
    if (blockIdx.x == 0) fgvalid[t] = ((c >> 32) != 0ull) ? 1 : 0;
  }
}

// ---------------------------------------------------------------------------
// Kernel 3: gather rois / labels / class-scattered bbox regression targets
// Output layout (flat return order): rois[256*5] | labels[256] | targets[256*84]
// ---------------------------------------------------------------------------
__global__ void __launch_bounds__(256)
finalize_kernel(const float* __restrict__ all_rois,
                const float* __restrict__ gt_boxes,
                const int* __restrict__ gt_labels,
                const uint32_t* __restrict__ score,
                const int* __restrict__ keep,
                const int* __restrict__ fgvalid,
                float* __restrict__ out, int N) {
  const int r = threadIdx.x;
  const int R = 2 * TK;
  if (r >= R) return;
  float* rois_out   = out;
  float* labels_out = out + (size_t)R * 5;
  float* bt_out     = out + (size_t)R * 5 + R;

  const int i = keep[r];
  float rimg, rx1, ry1, rx2, ry2;
  if (i < N) {
    rimg = all_rois[(size_t)i * 5 + 0];
    rx1  = all_rois[(size_t)i * 5 + 1];
    ry1  = all_rois[(size_t)i * 5 + 2];
    rx2  = all_rois[(size_t)i * 5 + 3];
    ry2  = all_rois[(size_t)i * 5 + 4];
  } else {
    int g = i - N;
    rimg = 0.0f;
    rx1 = gt_boxes[g * 4 + 0]; ry1 = gt_boxes[g * 4 + 1];
    rx2 = gt_boxes[g * 4 + 2]; ry2 = gt_boxes[g * 4 + 3];
  }
  rois_out[r * 5 + 0] = rimg;
  rois_out[r * 5 + 1] = rx1;
  rois_out[r * 5 + 2] = ry1;
  rois_out[r * 5 + 3] = rx2;
  rois_out[r * 5 + 4] = ry2;

  const int ga = (int)((score[i] >> 2) & 127u);
  int label = 0;
  if (r < TK && fgvalid[r]) label = gt_labels[ga];
  labels_out[r] = (float)label;

  // bbox_transform(ex=roi, gt=gt_boxes[ga])
  float gx1 = gt_boxes[ga * 4 + 0], gy1 = gt_boxes[ga * 4 + 1];
  float gx2 = gt_boxes[ga * 4 + 2], gy2 = gt_boxes[ga * 4 + 3];
  float ew = rx2 - rx1 + 1.0f, eh = ry2 - ry1 + 1.0f;
  float ecx = rx1 + 0.5f * ew, ecy = ry1 + 0.5f * eh;
  float gw = gx2 - gx1 + 1.0f, gh = gy2 - gy1 + 1.0f;
  float gcx = gx1 + 0.5f * gw, gcy = gy1 + 0.5f * gh;
  float tx = (gcx - ecx) / ew;
  float ty = (gcy - ecy) / eh;
  float tw = logf(gw / ew);
  float th = logf(gh / eh);

  for (int c = 0; c < 4 * NUM_CLASSES; ++c) bt_out[(size_t)r * 4 * NUM_CLASSES + c] = 0.0f;
  if (label > 0) {
    bt_out[(size_t)r * 4 * NUM_CLASSES + label * 4 + 0] = tx;
    bt_out[(size_t)r * 4 * NUM_CLASSES + label * 4 + 1] = ty;
    bt_out[(size_t)r * 4 * NUM_CLASSES + label * 4 + 2] = tw;
    bt_out[(size_t)r * 4 * NUM_CLASSES + label * 4 + 3] = th;
  }
}

// ---------------------------------------------------------------------------
extern "C" void kernel_launch(void* const* d_in, const int* in_sizes, int n_in,
                              void* d_out, int out_size, void* d_ws, size_t ws_size,
                              hipStream_t stream) {
  const float* all_rois = (const float*)d_in[0];
  const float* gt_boxes = (const float*)d_in[1];
  const int*   gt_labels = (const int*)d_in[2];
  const int N = in_sizes[0] / 5;
  const int G = in_sizes[2];
  const int M = N + G;

  uint32_t* score = (uint32_t*)d_ws;
  size_t score_bytes = (((size_t)M * 4) + 255) & ~(size_t)255;
  int* keep    = (int*)((char*)d_ws + score_bytes);
  int* fgvalid = keep + 2 * TK;
  float* out = (float*)d_out;

  const int blocks = (M + 255) / 256;
  score_kernel<<<blocks, 256, 0, stream>>>(all_rois, gt_boxes, score, N, M, G);
  select_kernel<<<2, SEL_THREADS, 0, stream>>>(score, M, keep, fgvalid);
  finalize_kernel<<<1, 256, 0, stream>>>(all_rois, gt_boxes, gt_labels, score,
                                         keep, fgvalid, out, N);
}

// Round 3
// 120.323 us; speedup vs baseline: 1.7639x; 1.7639x over previous
//
#include <hip/hip_runtime.h>
#include <stdint.h>

#define GMAX 128
#define TK 128            // top-k per mask (FG_ROIS_PER_IMAGE = BG_ROIS_PER_IMAGE = 128)
#define NBINS 4096
#define CAND_MAX 4096
#define NUM_CLASSES 21

// ---------------------------------------------------------------------------
// JAX threefry2x32 block cipher (key = [hi32(seed), lo32(seed)] = [0, 42])
// ---------------------------------------------------------------------------
__device__ __forceinline__ void threefry2x32(uint32_t k0, uint32_t k1,
                                             uint32_t& x0, uint32_t& x1) {
  uint32_t ks0 = k0, ks1 = k1, ks2 = k0 ^ k1 ^ 0x1BD11BDAu;
  x0 += ks0; x1 += ks1;
#define TF_ROUND(r) { x0 += x1; x1 = (x1 << (r)) | (x1 >> (32 - (r))); x1 ^= x0; }
  TF_ROUND(13) TF_ROUND(15) TF_ROUND(26) TF_ROUND(6)
  x0 += ks1; x1 += ks2 + 1u;
  TF_ROUND(17) TF_ROUND(29) TF_ROUND(16) TF_ROUND(24)
  x0 += ks2; x1 += ks0 + 2u;
  TF_ROUND(13) TF_ROUND(15) TF_ROUND(26) TF_ROUND(6)
  x0 += ks0; x1 += ks1 + 3u;
  TF_ROUND(17) TF_ROUND(29) TF_ROUND(16) TF_ROUND(24)
  x0 += ks1; x1 += ks2 + 4u;
  TF_ROUND(13) TF_ROUND(15) TF_ROUND(26) TF_ROUND(6)
  x0 += ks2; x1 += ks0 + 5u;
#undef TF_ROUND
}

// ---------------------------------------------------------------------------
// Kernel 0: zero the global histograms + candidate counters
// (d_ws is re-poisoned to 0xAA before every timed launch)
// ---------------------------------------------------------------------------
__global__ void __launch_bounds__(1024)
init_kernel(uint32_t* __restrict__ hist, int* __restrict__ meta) {
  int i = blockIdx.x * 1024 + threadIdx.x;
  if (i < 2 * NBINS) hist[i] = 0u;
  if (i < 4) meta[i] = 0;     // meta[0..1]=Bth (set later), meta[2..3]=cnt
}

// ---------------------------------------------------------------------------
// Kernel 1: per-ROI max-IoU, argmax (first-max), partitionable threefry
// uniform -> packed score word [ubits23 << 9 | gt(7b) << 2 | fg << 1 | bg]
// + global histogram of ubits top-12 bits per mask (fused: this kernel
// already touches every element).
// ---------------------------------------------------------------------------
__global__ void __launch_bounds__(256)
score_kernel(const float* __restrict__ all_rois,   // [N,5]
             const float* __restrict__ gt_boxes,   // [G,4]
             uint32_t* __restrict__ score,         // [M]
             uint32_t* __restrict__ hist,          // [2*NBINS] fg|bg
             int N, int M, int G) {
  __shared__ float sgx1[GMAX], sgy1[GMAX], sgx2[GMAX], sgy2[GMAX], sga[GMAX];
  const int t = threadIdx.x;
  if (t < G) {
    float x1 = gt_boxes[t * 4 + 0];
    float y1 = gt_boxes[t * 4 + 1];
    float x2 = gt_boxes[t * 4 + 2];
    float y2 = gt_boxes[t * 4 + 3];
    sgx1[t] = x1; sgy1[t] = y1; sgx2[t] = x2; sgy2[t] = y2;
    sga[t] = __fmul_rn(__fadd_rn(__fsub_rn(x2, x1), 1.0f),
                       __fadd_rn(__fsub_rn(y2, y1), 1.0f));
  }
  __syncthreads();
  const int i = blockIdx.x * 256 + t;
  if (i >= M) return;

  float bx1, by1, bx2, by2;
  if (i < N) {
    bx1 = all_rois[(size_t)i * 5 + 1];
    by1 = all_rois[(size_t)i * 5 + 2];
    bx2 = all_rois[(size_t)i * 5 + 3];
    by2 = all_rois[(size_t)i * 5 + 4];
  } else {
    int g = i - N;
    bx1 = sgx1[g]; by1 = sgy1[g]; bx2 = sgx2[g]; by2 = sgy2[g];
  }
  const float area = __fmul_rn(__fadd_rn(__fsub_rn(bx2, bx1), 1.0f),
                               __fadd_rn(__fsub_rn(by2, by1), 1.0f));
  float best = -1.0f;
  int bi = 0;
  for (int g = 0; g < G; ++g) {
    float ix1 = fmaxf(bx1, sgx1[g]);
    float iy1 = fmaxf(by1, sgy1[g]);
    float ix2 = fminf(bx2, sgx2[g]);
    float iy2 = fminf(by2, sgy2[g]);
    float iw = fmaxf(__fadd_rn(__fsub_rn(ix2, ix1), 1.0f), 0.0f);
    float ih = fmaxf(__fadd_rn(__fsub_rn(iy2, iy1), 1.0f), 0.0f);
    float inter = __fmul_rn(iw, ih);
    float uni = __fsub_rn(__fadd_rn(area, sga[g]), inter);
    float ov = __fdiv_rn(inter, uni);               // IEEE-rounded, matches XLA
    if (ov > best) { best = ov; bi = g; }           // first-max == jnp.argmax
  }

  // partitionable threefry: counter (hi=0, lo=i), output = x0 ^ x1
  uint32_t cx0 = 0u, cx1 = (uint32_t)i;
  threefry2x32(0u, 42u, cx0, cx1);
  uint32_t ubits = (cx0 ^ cx1) >> 9;                // mantissa of u in [0,1)

  uint32_t fg = (best >= 0.5f) ? 1u : 0u;
  uint32_t bg = (!fg && best >= 0.1f) ? 1u : 0u;
  score[i] = (ubits << 9) | ((uint32_t)bi << 2) | (fg << 1) | bg;
  if (fg)      atomicAdd(&hist[ubits >> 11], 1u);
  else if (bg) atomicAdd(&hist[NBINS + (ubits >> 11)], 1u);
}

// ---------------------------------------------------------------------------
// Kernel 2: per-mask threshold bin from the histogram (1 block).
// Suffix-scan; Bth = smallest bin s.t. count(bin >= Bth) >= TK, or -1 if the
// mask has < TK members (fallback path).
// ---------------------------------------------------------------------------
__global__ void __launch_bounds__(1024)
threshold_kernel(const uint32_t* __restrict__ hist, int* __restrict__ meta) {
  __shared__ uint32_t gs[1024];
  __shared__ int s_jstar;
  const int t = threadIdx.x;
  for (int m = 0; m < 2; ++m) {
    const uint32_t* h = hist + m * NBINS;
    if (t == 0) s_jstar = -1;
    __syncthreads();
    gs[t] = h[4 * t] + h[4 * t + 1] + h[4 * t + 2] + h[4 * t + 3];
    __syncthreads();
    for (int d = 1; d < 1024; d <<= 1) {
      uint32_t add = (t + d < 1024) ? gs[t + d] : 0u;
      __syncthreads();
      gs[t] += add;
      __syncthreads();
    }
    if (gs[t] >= (uint32_t)TK && (t == 1023 || gs[t + 1] < (uint32_t)TK))
      s_jstar = t;
    __syncthreads();
    if (t == 0) {
      int B = -1;
      if (s_jstar >= 0) {
        int j = s_jstar;
        uint32_t base = (j < 1023) ? gs[j + 1] : 0u;
        B = 4 * j;
        for (int b = 4 * j + 3; b >= 4 * j; --b) {
          base += h[b];
          if (base >= (uint32_t)TK) { B = b; break; }
        }
      }
      meta[m] = B;
    }
    __syncthreads();
  }
}

// ---------------------------------------------------------------------------
// Kernel 3: grid-parallel compact of candidates (bin >= Bth, or all masked
// in fallback). ~TK + epsilon appends per mask -> negligible atomic traffic.
// ---------------------------------------------------------------------------
__global__ void __launch_bounds__(1024)
compact_kernel(const uint32_t* __restrict__ score, int M,
               const int* __restrict__ meta_bth, int* __restrict__ meta_cnt,
               uint64_t* __restrict__ cand) {
  const int i = blockIdx.x * 1024 + threadIdx.x;
  if (i >= M) return;
  uint32_t s = score[i];
  uint32_t mb = s & 3u;
  if (!mb) return;
  const int m = (mb & 2u) ? 0 : 1;
  const int Bth = meta_bth[m];
  if (Bth >= 0 && (int)(s >> 20) < Bth) return;
  int p = atomicAdd(&meta_cnt[m], 1);
  if (p < CAND_MAX)
    cand[(size_t)m * CAND_MAX + p] =
        (((uint64_t)((s >> 9) + 1u)) << 32) | (uint64_t)(~(uint32_t)i);
}

// ---------------------------------------------------------------------------
// Kernel 4: sort candidates (bitonic, desc; key ((ubits+1)<<32)|~i reproduces
// XLA stable top_k + where(mask,u,-1.0) padding) and fused finalize:
// rois / labels / class-scattered bbox targets.
// Output layout: rois[256*5] | labels[256] | targets[256*84]
// ---------------------------------------------------------------------------
__global__ void __launch_bounds__(1024)
final_kernel(const float* __restrict__ all_rois,
             const float* __restrict__ gt_boxes,
             const int* __restrict__ gt_labels,
             const uint32_t* __restrict__ score,
             const uint64_t* __restrict__ cand_g,
             const int* __restrict__ meta,
             float* __restrict__ out, int N, int M) {
  __shared__ uint64_t cand[CAND_MAX];
  __shared__ int keep[2 * TK];
  __shared__ int fgvalid[TK];
  __shared__ float s_tx[2 * TK], s_ty[2 * TK], s_tw[2 * TK], s_th[2 * TK];
  __shared__ int s_label[2 * TK];
  const int t = threadIdx.x;

  for (int m = 0; m < 2; ++m) {
    int cnt = meta[2 + m]; if (cnt > CAND_MAX) cnt = CAND_MAX;
    const int Bth = meta[m];
    int P = TK;
    while (P < cnt) P <<= 1;
    for (int p = t; p < P; p += 1024)
      cand[p] = (p < cnt) ? cand_g[(size_t)m * CAND_MAX + p] : 0ull;
    __syncthreads();
    for (int k = 2; k <= P; k <<= 1) {
      for (int j = k >> 1; j > 0; j >>= 1) {
        for (int idx = t; idx < P; idx += 1024) {
          int l = idx ^ j;
          if (l > idx) {
            uint64_t a = cand[idx], b = cand[l];
            bool swp = ((idx & k) == 0) ? (a < b) : (a > b);
            if (swp) { cand[idx] = b; cand[l] = a; }
          }
        }
        __syncthreads();
      }
    }
    if (Bth < 0 && t == 0) {      // fewer than TK masked: pad with lowest-index
      int fill = cnt;             // non-masked (JAX -1.0 tie semantics)
      uint32_t mask_bit = (m == 0) ? 2u : 1u;
      for (int i = 0; i < M && fill < TK; ++i)
        if (!(score[i] & mask_bit)) cand[fill++] = (uint64_t)(~(uint32_t)i);
    }
    __syncthreads();
    if (t < TK) {
      uint64_t c = cand[t];
      keep[m * TK + t] = (int)(~(uint32_t)(c & 0xFFFFFFFFull));
      if (m == 0) fgvalid[t] = ((c >> 32) != 0ull) ? 1 : 0;
    }
    __syncthreads();
  }

  const int R = 2 * TK;
  float* rois_out   = out;
  float* labels_out = out + (size_t)R * 5;
  float* bt_out     = out + (size_t)R * 5 + R;

  if (t < R) {
    const int i = keep[t];
    float rimg, rx1, ry1, rx2, ry2;
    if (i < N) {
      rimg = all_rois[(size_t)i * 5 + 0];
      rx1  = all_rois[(size_t)i * 5 + 1];
      ry1  = all_rois[(size_t)i * 5 + 2];
      rx2  = all_rois[(size_t)i * 5 + 3];
      ry2  = all_rois[(size_t)i * 5 + 4];
    } else {
      int g = i - N;
      rimg = 0.0f;
      rx1 = gt_boxes[g * 4 + 0]; ry1 = gt_boxes[g * 4 + 1];
      rx2 = gt_boxes[g * 4 + 2]; ry2 = gt_boxes[g * 4 + 3];
    }
    rois_out[t * 5 + 0] = rimg;
    rois_out[t * 5 + 1] = rx1;
    rois_out[t * 5 + 2] = ry1;
    rois_out[t * 5 + 3] = rx2;
    rois_out[t * 5 + 4] = ry2;

    const int ga = (int)((score[i] >> 2) & 127u);
    int label = (t < TK && fgvalid[t]) ? gt_labels[ga] : 0;
    labels_out[t] = (float)label;
    s_label[t] = label;

    float gx1 = gt_boxes[ga * 4 + 0], gy1 = gt_boxes[ga * 4 + 1];
    float gx2 = gt_boxes[ga * 4 + 2], gy2 = gt_boxes[ga * 4 + 3];
    float ew = rx2 - rx1 + 1.0f, eh = ry2 - ry1 + 1.0f;
    float ecx = rx1 + 0.5f * ew, ecy = ry1 + 0.5f * eh;
    float gw = gx2 - gx1 + 1.0f, gh = gy2 - gy1 + 1.0f;
    float gcx = gx1 + 0.5f * gw, gcy = gy1 + 0.5f * gh;
    s_tx[t] = (gcx - ecx) / ew;
    s_ty[t] = (gcy - ecy) / eh;
    s_tw[t] = logf(gw / ew);
    s_th[t] = logf(gh / eh);
  }
  __syncthreads();

  const int TOT = R * 4 * NUM_CLASSES;
  for (int idx = t; idx < TOT; idx += 1024) {
    int r = idx / (4 * NUM_CLASSES);
    int c = idx - r * (4 * NUM_CLASSES);
    int lab = s_label[r];
    float v = 0.0f;
    if (lab > 0 && (c >> 2) == lab) {
      int cc = c & 3;
      v = (cc == 0) ? s_tx[r] : (cc == 1) ? s_ty[r] : (cc == 2) ? s_tw[r] : s_th[r];
    }
    bt_out[idx] = v;
  }
}

// ---------------------------------------------------------------------------
extern "C" void kernel_launch(void* const* d_in, const int* in_sizes, int n_in,
                              void* d_out, int out_size, void* d_ws, size_t ws_size,
                              hipStream_t stream) {
  const float* all_rois = (const float*)d_in[0];
  const float* gt_boxes = (const float*)d_in[1];
  const int*   gt_labels = (const int*)d_in[2];
  const int N = in_sizes[0] / 5;
  const int G = in_sizes[2];
  const int M = N + G;

  // workspace layout
  char* ws = (char*)d_ws;
  uint32_t* score = (uint32_t*)ws;
  size_t off = (((size_t)M * 4) + 255) & ~(size_t)255;
  uint32_t* hist = (uint32_t*)(ws + off);  off += 2 * NBINS * 4;
  int* meta = (int*)(ws + off);            off += 256;   // [Bth_fg,Bth_bg,cnt_fg,cnt_bg]
  uint64_t* cand = (uint64_t*)(ws + off);  off += 2 * (size_t)CAND_MAX * 8;
  float* out = (float*)d_out;

  init_kernel<<<(2 * NBINS + 1023) / 1024, 1024, 0, stream>>>(hist, meta);
  score_kernel<<<(M + 255) / 256, 256, 0, stream>>>(all_rois, gt_boxes, score,
                                                    hist, N, M, G);
  threshold_kernel<<<1, 1024, 0, stream>>>(hist, meta);
  compact_kernel<<<(M + 1023) / 1024, 1024, 0, stream>>>(score, M, meta,
                                                         meta + 2, cand);
  final_kernel<<<1, 1024, 0, stream>>>(all_rois, gt_boxes, gt_labels, score,
                                       cand, meta, out, N, M);
}